// Round 1
// baseline (749.354 us; speedup 1.0000x reference)
//
#include <hip/hip_runtime.h>

#define N_NODES 100000
#define N_EDGES 1600000
#define D 128

// ---------------- CSR build ----------------

__global__ void k_zero(int* __restrict__ p, int n) {
  int i = blockIdx.x * blockDim.x + threadIdx.x;
  if (i < n) p[i] = 0;
}

__global__ void k_count(const int* __restrict__ dst, int* __restrict__ cnt) {
  int e = blockIdx.x * blockDim.x + threadIdx.x;
  if (e < N_EDGES) atomicAdd(&cnt[dst[e]], 1);
}

// per-256-chunk exclusive scan of cnt -> rowptr (local), block totals -> bsum
__global__ void k_scan1(const int* __restrict__ cnt, int* __restrict__ rowptr,
                        int* __restrict__ bsum, int n) {
  __shared__ int s[256];
  int tid = threadIdx.x;
  int i = blockIdx.x * 256 + tid;
  int v = (i < n) ? cnt[i] : 0;
  s[tid] = v;
  __syncthreads();
  for (int off = 1; off < 256; off <<= 1) {
    int t = (tid >= off) ? s[tid - off] : 0;
    __syncthreads();
    s[tid] += t;
    __syncthreads();
  }
  if (i < n) rowptr[i] = s[tid] - v;   // exclusive within chunk
  if (tid == 255) bsum[blockIdx.x] = s[255];
}

// single-block exclusive scan of block sums (nb <= 512)
__global__ void k_scan2(int* __restrict__ bsum, int nb) {
  __shared__ int s[512];
  int tid = threadIdx.x;
  int v = (tid < nb) ? bsum[tid] : 0;
  s[tid] = v;
  __syncthreads();
  for (int off = 1; off < 512; off <<= 1) {
    int t = (tid >= off) ? s[tid - off] : 0;
    __syncthreads();
    s[tid] += t;
    __syncthreads();
  }
  if (tid < nb) bsum[tid] = s[tid] - v;
}

__global__ void k_scan3(int* __restrict__ rowptr, const int* __restrict__ bsum, int n) {
  int i = blockIdx.x * 256 + threadIdx.x;
  if (i < n) rowptr[i] += bsum[blockIdx.x];
  if (i == 0) rowptr[n] = N_EDGES;
}

__global__ void k_fill(const int* __restrict__ src, const int* __restrict__ dst,
                       const int* __restrict__ rowptr, int* __restrict__ fill,
                       int* __restrict__ csr) {
  int e = blockIdx.x * blockDim.x + threadIdx.x;
  if (e < N_EDGES) {
    int d = dst[e];
    int slot = rowptr[d] + atomicAdd(&fill[d], 1);
    csr[slot] = src[e];
  }
}

// ---------------- mean aggregation (CSR, no atomics) ----------------
// 32 lanes per node, float4 per lane -> one full 512B row per edge, coalesced.
__global__ void k_agg(const float* __restrict__ h, const int* __restrict__ rowptr,
                      const int* __restrict__ csr, float* __restrict__ mean) {
  int node = blockIdx.x * 8 + (threadIdx.x >> 5);
  int lane = threadIdx.x & 31;
  if (node >= N_NODES) return;
  int beg = rowptr[node], end = rowptr[node + 1];
  float4 acc = make_float4(0.f, 0.f, 0.f, 0.f);
  for (int e = beg; e < end; ++e) {
    int s = csr[e];
    const float4 v = *reinterpret_cast<const float4*>(h + s * D + lane * 4);
    acc.x += v.x; acc.y += v.y; acc.z += v.z; acc.w += v.w;
  }
  float inv = (end > beg) ? 1.0f / (float)(end - beg) : 0.0f;  // cnt==0 -> mean 0
  acc.x *= inv; acc.y *= inv; acc.z *= inv; acc.w *= inv;
  *reinterpret_cast<float4*>(mean + node * D + lane * 4) = acc;
}

// ---------------- fused linear: out = A1@W1 + A2@W2 + b (opt. ReLU) ----------
// K = 256 (two 128-halves from A1/W1 then A2/W2), KC=64 chunks staged in LDS.
#define TN 64
#define KC 64

__global__ __launch_bounds__(256) void k_lin(
    const float* __restrict__ A1, const float* __restrict__ A2,
    const float* __restrict__ W1, const float* __restrict__ W2,
    const float* __restrict__ bias, float* __restrict__ out, int relu) {
  __shared__ float Alds[TN][KC + 4];   // +4 pad: keeps 16B alignment, breaks conflicts
  __shared__ float Wlds[KC][D];
  int tid = threadIdx.x;
  int n0 = blockIdx.x * TN;
  int jc = (tid & 15) * 8;        // 8 output cols per thread
  int ng = (tid >> 4) * 4;        // 4 nodes per thread

  float acc[4][8];
#pragma unroll
  for (int i = 0; i < 4; ++i)
#pragma unroll
    for (int j = 0; j < 8; ++j) acc[i][j] = 0.f;

  for (int chunk = 0; chunk < 4; ++chunk) {
    const float* A = (chunk < 2) ? A1 : A2;
    const float* W = (chunk < 2) ? W1 : W2;
    int k0 = (chunk & 1) * KC;
    // stage A tile: 64 nodes x 64 k
#pragma unroll
    for (int i = 0; i < 4; ++i) {
      int li = tid + 256 * i;     // 0..1023
      int row = li >> 4;          // 0..63
      int c4 = li & 15;           // 0..15
      int n = n0 + row;
      float4 v = (n < N_NODES)
                     ? *reinterpret_cast<const float4*>(A + n * D + k0 + c4 * 4)
                     : make_float4(0.f, 0.f, 0.f, 0.f);
      *reinterpret_cast<float4*>(&Alds[row][c4 * 4]) = v;
    }
    // stage W chunk: 64 k x 128 cols
#pragma unroll
    for (int i = 0; i < 8; ++i) {
      int li = tid + 256 * i;     // 0..2047
      int k = li >> 5;            // 0..63
      int c4 = li & 31;
      float4 v = *reinterpret_cast<const float4*>(W + (k0 + k) * D + c4 * 4);
      *reinterpret_cast<float4*>(&Wlds[k][c4 * 4]) = v;
    }
    __syncthreads();
#pragma unroll 8
    for (int k = 0; k < KC; ++k) {
      float4 w0 = *reinterpret_cast<const float4*>(&Wlds[k][jc]);
      float4 w1 = *reinterpret_cast<const float4*>(&Wlds[k][jc + 4]);
#pragma unroll
      for (int i = 0; i < 4; ++i) {
        float a = Alds[ng + i][k];
        acc[i][0] += a * w0.x; acc[i][1] += a * w0.y;
        acc[i][2] += a * w0.z; acc[i][3] += a * w0.w;
        acc[i][4] += a * w1.x; acc[i][5] += a * w1.y;
        acc[i][6] += a * w1.z; acc[i][7] += a * w1.w;
      }
    }
    __syncthreads();
  }
  float4 b0 = *reinterpret_cast<const float4*>(bias + jc);
  float4 b1 = *reinterpret_cast<const float4*>(bias + jc + 4);
#pragma unroll
  for (int i = 0; i < 4; ++i) {
    int n = n0 + ng + i;
    if (n >= N_NODES) continue;
    float o[8];
    o[0] = acc[i][0] + b0.x; o[1] = acc[i][1] + b0.y;
    o[2] = acc[i][2] + b0.z; o[3] = acc[i][3] + b0.w;
    o[4] = acc[i][4] + b1.x; o[5] = acc[i][5] + b1.y;
    o[6] = acc[i][6] + b1.z; o[7] = acc[i][7] + b1.w;
    if (relu) {
#pragma unroll
      for (int j = 0; j < 8; ++j) o[j] = fmaxf(o[j], 0.f);
    }
    float4 s0 = make_float4(o[0], o[1], o[2], o[3]);
    float4 s1 = make_float4(o[4], o[5], o[6], o[7]);
    *reinterpret_cast<float4*>(out + n * D + jc) = s0;
    *reinterpret_cast<float4*>(out + n * D + jc + 4) = s1;
  }
}

// ---------------- launch ----------------

extern "C" void kernel_launch(void* const* d_in, const int* in_sizes, int n_in,
                              void* d_out, int out_size, void* d_ws, size_t ws_size,
                              hipStream_t stream) {
  const float* x   = (const float*)d_in[0];
  const int*   ei  = (const int*)d_in[1];
  const float* Wl1 = (const float*)d_in[2];
  const float* Wr1 = (const float*)d_in[3];
  const float* b1  = (const float*)d_in[4];
  const float* Wl2 = (const float*)d_in[5];
  const float* Wr2 = (const float*)d_in[6];
  const float* b2  = (const float*)d_in[7];
  float* out = (float*)d_out;

  const int* esrc = ei;
  const int* edst = ei + N_EDGES;

  // workspace layout (16B aligned pieces)
  char* p = (char*)d_ws;
  int* cnt    = (int*)p;                 p += (size_t)N_NODES * 4;        // 400000
  int* fill   = (int*)p;                 p += (size_t)N_NODES * 4;        // 400000
  int* rowptr = (int*)p;                 p += ((size_t)(N_NODES + 1) * 4 + 12) & ~(size_t)15;
  int* bsum   = (int*)p;                 p += 512 * 4;
  int* csr    = (int*)p;                 p += (size_t)N_EDGES * 4;        // 6.4MB
  float* mean = (float*)p;               p += (size_t)N_NODES * D * 4;    // 51.2MB
  float* hbuf = (float*)p;               p += (size_t)N_NODES * D * 4;    // 51.2MB

  const int nscan = (N_NODES + 255) / 256;  // 391

  // CSR build (edge_index identical for both layers -> build once)
  k_zero<<<(2 * N_NODES + 255) / 256, 256, 0, stream>>>(cnt, 2 * N_NODES); // cnt+fill
  k_count<<<(N_EDGES + 255) / 256, 256, 0, stream>>>(edst, cnt);
  k_scan1<<<nscan, 256, 0, stream>>>(cnt, rowptr, bsum, N_NODES);
  k_scan2<<<1, 512, 0, stream>>>(bsum, nscan);
  k_scan3<<<nscan, 256, 0, stream>>>(rowptr, bsum, N_NODES);
  k_fill<<<(N_EDGES + 255) / 256, 256, 0, stream>>>(esrc, edst, rowptr, fill, csr);

  // layer 1: h = relu(mean(x) @ Wl1 + x @ Wr1 + b1)
  k_agg<<<(N_NODES + 7) / 8, 256, 0, stream>>>(x, rowptr, csr, mean);
  k_lin<<<(N_NODES + TN - 1) / TN, 256, 0, stream>>>(mean, x, Wl1, Wr1, b1, hbuf, 1);

  // layer 2: out = mean(h) @ Wl2 + h @ Wr2 + b2
  k_agg<<<(N_NODES + 7) / 8, 256, 0, stream>>>(hbuf, rowptr, csr, mean);
  k_lin<<<(N_NODES + TN - 1) / TN, 256, 0, stream>>>(mean, hbuf, Wl2, Wr2, b2, out, 0);
}

// Round 4
// 488.748 us; speedup vs baseline: 1.5332x; 1.5332x over previous
//
#include <hip/hip_runtime.h>
#include <stdint.h>

#define N_NODES 100000
#define N_EDGES 1600000
#define D 128

typedef unsigned int uint32;
typedef __attribute__((ext_vector_type(8))) short short8;   // 8 bf16 = 4 VGPRs
typedef __attribute__((ext_vector_type(4))) float f32x4;

__device__ __forceinline__ unsigned short f2bf(float f) {
  unsigned u = __builtin_bit_cast(unsigned, f);
  u += 0x7fffu + ((u >> 16) & 1u);          // round-to-nearest-even
  return (unsigned short)(u >> 16);
}
__device__ __forceinline__ float bflo(unsigned v) {
  return __builtin_bit_cast(float, v << 16);
}
__device__ __forceinline__ float bfhi(unsigned v) {
  return __builtin_bit_cast(float, v & 0xffff0000u);
}

// ---------------- CSR build ----------------

__global__ void k_zero(int* __restrict__ p, int n) {
  int i = blockIdx.x * blockDim.x + threadIdx.x;
  if (i < n) p[i] = 0;
}

__global__ void k_count(const int* __restrict__ dst, int* __restrict__ cnt) {
  int e = blockIdx.x * blockDim.x + threadIdx.x;
  if (e < N_EDGES) atomicAdd(&cnt[dst[e]], 1);
}

__global__ void k_scan1(const int* __restrict__ cnt, int* __restrict__ rowptr,
                        int* __restrict__ bsum, int n) {
  __shared__ int s[256];
  int tid = threadIdx.x;
  int i = blockIdx.x * 256 + tid;
  int v = (i < n) ? cnt[i] : 0;
  s[tid] = v;
  __syncthreads();
  for (int off = 1; off < 256; off <<= 1) {
    int t = (tid >= off) ? s[tid - off] : 0;
    __syncthreads();
    s[tid] += t;
    __syncthreads();
  }
  if (i < n) rowptr[i] = s[tid] - v;
  if (tid == 255) bsum[blockIdx.x] = s[255];
}

__global__ void k_scan2(int* __restrict__ bsum, int nb) {
  __shared__ int s[512];
  int tid = threadIdx.x;
  int v = (tid < nb) ? bsum[tid] : 0;
  s[tid] = v;
  __syncthreads();
  for (int off = 1; off < 512; off <<= 1) {
    int t = (tid >= off) ? s[tid - off] : 0;
    __syncthreads();
    s[tid] += t;
    __syncthreads();
  }
  if (tid < nb) bsum[tid] = s[tid] - v;
}

__global__ void k_scan3(int* __restrict__ rowptr, const int* __restrict__ bsum, int n) {
  int i = blockIdx.x * 256 + threadIdx.x;
  if (i < n) rowptr[i] += bsum[blockIdx.x];
  if (i == 0) rowptr[n] = N_EDGES;
}

__global__ void k_fill(const int* __restrict__ src, const int* __restrict__ dst,
                       const int* __restrict__ rowptr, int* __restrict__ fill,
                       int* __restrict__ csr) {
  int e = blockIdx.x * blockDim.x + threadIdx.x;
  if (e < N_EDGES) {
    int d = dst[e];
    int slot = rowptr[d] + atomicAdd(&fill[d], 1);
    csr[slot] = src[e];
  }
}

// ---------------- casts / weight packing ----------------

// f32 -> bf16, 8 elements per thread
__global__ void k_cast(const float* __restrict__ in, unsigned short* __restrict__ ob, int n8) {
  int i = blockIdx.x * blockDim.x + threadIdx.x;
  if (i >= n8) return;
  float4 a = *reinterpret_cast<const float4*>(in + (size_t)i * 8);
  float4 b = *reinterpret_cast<const float4*>(in + (size_t)i * 8 + 4);
  uint4 o;
  o.x = (uint32)f2bf(a.x) | ((uint32)f2bf(a.y) << 16);
  o.y = (uint32)f2bf(a.z) | ((uint32)f2bf(a.w) << 16);
  o.z = (uint32)f2bf(b.x) | ((uint32)f2bf(b.y) << 16);
  o.w = (uint32)f2bf(b.z) | ((uint32)f2bf(b.w) << 16);
  *reinterpret_cast<uint4*>(ob + (size_t)i * 8) = o;
}

// Pack W = [Wl ; Wr] (K=256, N=128) into exact B-fragment order for
// mfma_f32_16x16x32_bf16: B[k = quad*8+j][n = lane&15].
// Linear index t = (((ng*8 + ks)*2 + tile)*64 + lane)*8 + j  -> 32768 total.
__global__ void k_prepw(const float* __restrict__ Wl, const float* __restrict__ Wr,
                        unsigned short* __restrict__ Wp) {
  int t = blockIdx.x * 256 + threadIdx.x;
  if (t >= 256 * 128) return;
  int j = t & 7;
  int lane = (t >> 3) & 63;
  int tile = (t >> 9) & 1;
  int ks = (t >> 10) & 7;
  int ng = (t >> 13) & 3;
  int k = ks * 32 + (lane >> 4) * 8 + j;
  int n = ng * 32 + tile * 16 + (lane & 15);
  float w = (k < 128) ? Wl[k * 128 + n] : Wr[(k - 128) * 128 + n];
  Wp[t] = f2bf(w);
}

// ---------------- mean aggregation, bf16 rows (256B gather) ----------------
// 16 lanes per node, 16B per lane. Accumulate f32, emit bf16 mean.
__global__ void k_aggb(const unsigned short* __restrict__ hb, const int* __restrict__ rowptr,
                       const int* __restrict__ csr, unsigned short* __restrict__ meanb) {
  int node = blockIdx.x * 16 + (threadIdx.x >> 4);
  int l = threadIdx.x & 15;
  if (node >= N_NODES) return;
  int beg = rowptr[node], end = rowptr[node + 1];
  float acc[8] = {0.f, 0.f, 0.f, 0.f, 0.f, 0.f, 0.f, 0.f};
  for (int e = beg; e < end; ++e) {
    int s = csr[e];
    uint4 v = *reinterpret_cast<const uint4*>(hb + (size_t)s * D + l * 8);
    acc[0] += bflo(v.x); acc[1] += bfhi(v.x);
    acc[2] += bflo(v.y); acc[3] += bfhi(v.y);
    acc[4] += bflo(v.z); acc[5] += bfhi(v.z);
    acc[6] += bflo(v.w); acc[7] += bfhi(v.w);
  }
  float inv = (end > beg) ? 1.0f / (float)(end - beg) : 0.0f;
  uint4 o;
  o.x = (uint32)f2bf(acc[0] * inv) | ((uint32)f2bf(acc[1] * inv) << 16);
  o.y = (uint32)f2bf(acc[2] * inv) | ((uint32)f2bf(acc[3] * inv) << 16);
  o.z = (uint32)f2bf(acc[4] * inv) | ((uint32)f2bf(acc[5] * inv) << 16);
  o.w = (uint32)f2bf(acc[6] * inv) | ((uint32)f2bf(acc[7] * inv) << 16);
  *reinterpret_cast<uint4*>(meanb + (size_t)node * D + l * 8) = o;
}

// ---------------- MFMA GEMM: C[M,128] = [meanb|xh] @ Wp + b ----------------
// 4 waves/block, wave w owns cols [w*32, w*32+32). B frags live in registers
// (loaded once). A streamed global->frag, no LDS, no barriers.
#define GRID_GEMM 1024

__global__ __launch_bounds__(256) void k_gemm(
    const unsigned short* __restrict__ Am, const unsigned short* __restrict__ Axh,
    const unsigned short* __restrict__ Wp, const float* __restrict__ bias,
    void* __restrict__ outp, int relu_bf16_out, int nTiles) {
  int wave = threadIdx.x >> 6;
  int lane = threadIdx.x & 63;
  int q = lane >> 4;          // quad: k-offset q*8 in frags, row-offset q*4 in C
  int r = lane & 15;          // A row within tile / C col within tile

  short8 Bf[8][2];
  const unsigned short* wp = Wp + ((size_t)wave * 8 * 2) * 64 * 8 + lane * 8;
#pragma unroll
  for (int ks = 0; ks < 8; ++ks)
#pragma unroll
    for (int t = 0; t < 2; ++t)
      Bf[ks][t] = *reinterpret_cast<const short8*>(wp + (ks * 2 + t) * 512);

  float bia0 = bias[wave * 32 + r];
  float bia1 = bias[wave * 32 + 16 + r];

  for (int tile = blockIdx.x; tile < nTiles; tile += GRID_GEMM) {
    int row = tile * 16 + r;
    const unsigned short* am = Am + (size_t)row * D + q * 8;
    const unsigned short* ax = Axh + (size_t)row * D + q * 8;
    short8 A[8];
#pragma unroll
    for (int ks = 0; ks < 4; ++ks) A[ks] = *reinterpret_cast<const short8*>(am + ks * 32);
#pragma unroll
    for (int ks = 0; ks < 4; ++ks) A[4 + ks] = *reinterpret_cast<const short8*>(ax + ks * 32);

    f32x4 c0 = {0.f, 0.f, 0.f, 0.f}, c1 = {0.f, 0.f, 0.f, 0.f};
#pragma unroll
    for (int ks = 0; ks < 8; ++ks) {
      c0 = __builtin_amdgcn_mfma_f32_16x16x32_bf16(A[ks], Bf[ks][0], c0, 0, 0, 0);
      c1 = __builtin_amdgcn_mfma_f32_16x16x32_bf16(A[ks], Bf[ks][1], c1, 0, 0, 0);
    }

    int orow = tile * 16 + q * 4;   // C: col=lane&15, row=quad*4+reg
    if (relu_bf16_out) {
      unsigned short* ob = (unsigned short*)outp + (size_t)orow * D + wave * 32 + r;
#pragma unroll
      for (int g = 0; g < 4; ++g) {
        ob[(size_t)g * D] = f2bf(fmaxf(c0[g] + bia0, 0.f));
        ob[(size_t)g * D + 16] = f2bf(fmaxf(c1[g] + bia1, 0.f));
      }
    } else {
      float* of = (float*)outp + (size_t)orow * D + wave * 32 + r;
#pragma unroll
      for (int g = 0; g < 4; ++g) {
        of[(size_t)g * D] = c0[g] + bia0;
        of[(size_t)g * D + 16] = c1[g] + bia1;
      }
    }
  }
}

// ---------------- launch ----------------

extern "C" void kernel_launch(void* const* d_in, const int* in_sizes, int n_in,
                              void* d_out, int out_size, void* d_ws, size_t ws_size,
                              hipStream_t stream) {
  const float* x   = (const float*)d_in[0];
  const int*   ei  = (const int*)d_in[1];
  const float* Wl1 = (const float*)d_in[2];
  const float* Wr1 = (const float*)d_in[3];
  const float* b1  = (const float*)d_in[4];
  const float* Wl2 = (const float*)d_in[5];
  const float* Wr2 = (const float*)d_in[6];
  const float* b2  = (const float*)d_in[7];
  float* out = (float*)d_out;

  const int* esrc = ei;
  const int* edst = ei + N_EDGES;

  char* p = (char*)d_ws;
  auto take = [&](size_t bytes) {
    char* q = p;
    p += (bytes + 255) & ~(size_t)255;
    return q;
  };
  // cnt+fill CONTIGUOUS in one allocation: the combined k_zero(2*N) must
  // cover fill's tail (R2/R3 fault: 256B-rounded takes left a 128B gap ->
  // fill[99968..] stayed 0xAA -> csr[huge] write -> abort).
  int* cnt    = (int*)take((size_t)2 * N_NODES * 4);
  int* fill   = cnt + N_NODES;
  int* rowptr = (int*)take((size_t)(N_NODES + 1) * 4);
  int* bsum   = (int*)take(512 * 4);
  int* csr    = (int*)take((size_t)N_EDGES * 4);
  unsigned short* xb    = (unsigned short*)take((size_t)N_NODES * D * 2);
  unsigned short* hb    = (unsigned short*)take((size_t)N_NODES * D * 2);
  unsigned short* meanb = (unsigned short*)take((size_t)N_NODES * D * 2);
  unsigned short* Wp1   = (unsigned short*)take(256 * 128 * 2);
  unsigned short* Wp2   = (unsigned short*)take(256 * 128 * 2);

  const int nscan = (N_NODES + 255) / 256;   // 391
  const int nTiles = N_NODES / 16;           // 6250 (exact)

  // CSR build (shared by both layers)
  k_zero<<<(2 * N_NODES + 255) / 256, 256, 0, stream>>>(cnt, 2 * N_NODES);
  k_count<<<(N_EDGES + 255) / 256, 256, 0, stream>>>(edst, cnt);
  k_scan1<<<nscan, 256, 0, stream>>>(cnt, rowptr, bsum, N_NODES);
  k_scan2<<<1, 512, 0, stream>>>(bsum, nscan);
  k_scan3<<<nscan, 256, 0, stream>>>(rowptr, bsum, N_NODES);
  k_fill<<<(N_EDGES + 255) / 256, 256, 0, stream>>>(esrc, edst, rowptr, fill, csr);

  // bf16 prep
  k_cast<<<(N_NODES * D / 8 + 255) / 256, 256, 0, stream>>>(x, xb, N_NODES * D / 8);
  k_prepw<<<128, 256, 0, stream>>>(Wl1, Wr1, Wp1);
  k_prepw<<<128, 256, 0, stream>>>(Wl2, Wr2, Wp2);

  // layer 1: hb = relu([mean(xb)|xb] @ Wp1 + b1)   (bf16 out)
  k_aggb<<<(N_NODES + 15) / 16, 256, 0, stream>>>(xb, rowptr, csr, meanb);
  k_gemm<<<GRID_GEMM, 256, 0, stream>>>(meanb, xb, Wp1, b1, hb, 1, nTiles);

  // layer 2: out = [mean(hb)|hb] @ Wp2 + b2        (f32 out)
  k_aggb<<<(N_NODES + 15) / 16, 256, 0, stream>>>(hb, rowptr, csr, meanb);
  k_gemm<<<GRID_GEMM, 256, 0, stream>>>(meanb, hb, Wp2, b2, out, 0, nTiles);
}

// Round 5
// 447.612 us; speedup vs baseline: 1.6741x; 1.0919x over previous
//
#include <hip/hip_runtime.h>
#include <stdint.h>

#define N_NODES 100000
#define N_EDGES 1600000
#define D 128
#define NBUCK 196          // ceil(N_NODES / 512): bucket b = dst >> 9
#define PCHUNK 4096        // edges per k_part block

typedef unsigned int uint32;
typedef __attribute__((ext_vector_type(8))) short short8;   // 8 bf16 = 4 VGPRs
typedef __attribute__((ext_vector_type(4))) float f32x4;

__device__ __forceinline__ unsigned short f2bf(float f) {
  unsigned u = __builtin_bit_cast(unsigned, f);
  u += 0x7fffu + ((u >> 16) & 1u);          // round-to-nearest-even
  return (unsigned short)(u >> 16);
}
__device__ __forceinline__ float bflo(unsigned v) {
  return __builtin_bit_cast(float, v << 16);
}
__device__ __forceinline__ float bfhi(unsigned v) {
  return __builtin_bit_cast(float, v & 0xffff0000u);
}

// ---------------- CSR build ----------------

__global__ void k_zero(int* __restrict__ p, int n) {
  int i = blockIdx.x * blockDim.x + threadIdx.x;
  if (i < n) p[i] = 0;
}

__global__ void k_count(const int* __restrict__ dst, int* __restrict__ cnt) {
  int e = blockIdx.x * blockDim.x + threadIdx.x;
  if (e < N_EDGES) atomicAdd(&cnt[dst[e]], 1);
}

__global__ void k_scan1(const int* __restrict__ cnt, int* __restrict__ rowptr,
                        int* __restrict__ bsum, int n) {
  __shared__ int s[256];
  int tid = threadIdx.x;
  int i = blockIdx.x * 256 + tid;
  int v = (i < n) ? cnt[i] : 0;
  s[tid] = v;
  __syncthreads();
  for (int off = 1; off < 256; off <<= 1) {
    int t = (tid >= off) ? s[tid - off] : 0;
    __syncthreads();
    s[tid] += t;
    __syncthreads();
  }
  if (i < n) rowptr[i] = s[tid] - v;
  if (tid == 255) bsum[blockIdx.x] = s[255];
}

__global__ void k_scan2(int* __restrict__ bsum, int nb) {
  __shared__ int s[512];
  int tid = threadIdx.x;
  int v = (tid < nb) ? bsum[tid] : 0;
  s[tid] = v;
  __syncthreads();
  for (int off = 1; off < 512; off <<= 1) {
    int t = (tid >= off) ? s[tid - off] : 0;
    __syncthreads();
    s[tid] += t;
    __syncthreads();
  }
  if (tid < nb) bsum[tid] = s[tid] - v;
}

__global__ void k_scan3(int* __restrict__ rowptr, const int* __restrict__ bsum, int n) {
  int i = blockIdx.x * 256 + threadIdx.x;
  if (i < n) rowptr[i] += bsum[blockIdx.x];
  if (i == 0) rowptr[n] = N_EDGES;
}

// bfill[b] = start of bucket b's region = rowptr[b*512] (bucket == csr window!)
__global__ void k_binit(const int* __restrict__ rowptr, int* __restrict__ bfill) {
  int tid = threadIdx.x;   // 256
  int idx = tid * 512;
  if (idx > N_NODES) idx = N_NODES;
  bfill[tid] = rowptr[idx];
}

// Partition edges into dst-buckets (b = dst>>9) as (dst,src) pairs.
// Block-local LDS sort by bucket -> contiguous coalesced runs per bucket.
__global__ __launch_bounds__(256) void k_part(const int* __restrict__ src,
                                              const int* __restrict__ dst,
                                              int* __restrict__ bfill,
                                              uint2* __restrict__ pairs) {
  __shared__ uint2 buff[PCHUNK];     // 32 KB
  __shared__ uint2 sorted[PCHUNK];   // 32 KB
  __shared__ int hist[256], stmp[256], loff[256], cpos[256], base[256];
  int tid = threadIdx.x;
  int e0 = blockIdx.x * PCHUNK;
  int nv = N_EDGES - e0;
  if (nv > PCHUNK) nv = PCHUNK;

  hist[tid] = 0;
  __syncthreads();
  for (int i = tid; i < nv; i += 256) {
    int d = dst[e0 + i];
    int s = src[e0 + i];
    buff[i] = make_uint2((uint32)d, (uint32)s);
    atomicAdd(&hist[d >> 9], 1);
  }
  __syncthreads();
  // exclusive scan of hist (ladder)
  int v = hist[tid];
  stmp[tid] = v;
  __syncthreads();
  for (int off = 1; off < 256; off <<= 1) {
    int t = (tid >= off) ? stmp[tid - off] : 0;
    __syncthreads();
    stmp[tid] += t;
    __syncthreads();
  }
  loff[tid] = stmp[tid] - v;
  cpos[tid] = stmp[tid] - v;
  base[tid] = (v > 0) ? atomicAdd(&bfill[tid], v) : 0;  // reserve global run
  __syncthreads();
  // LDS scatter: group by bucket
  for (int i = tid; i < nv; i += 256) {
    uint2 p = buff[i];
    int r = atomicAdd(&cpos[p.x >> 9], 1);
    sorted[r] = p;
  }
  __syncthreads();
  // write runs: consecutive i -> consecutive global within each bucket run
  for (int i = tid; i < nv; i += 256) {
    uint2 p = sorted[i];
    int b = (int)(p.x >> 9);
    pairs[(size_t)base[b] + (i - loff[b])] = p;
  }
}

// Per-bucket scatter to csr: all writes land in a 32KB csr window -> L2-local.
__global__ __launch_bounds__(512) void k_fill2(const uint2* __restrict__ pairs,
                                               const int* __restrict__ rowptr,
                                               int* __restrict__ fill,
                                               int* __restrict__ csr) {
  int b = blockIdx.x;          // 0..NBUCK-1
  int lo = b << 9;
  int hi = lo + 512;
  if (hi > N_NODES) hi = N_NODES;
  int beg = rowptr[lo], end = rowptr[hi];
  for (int i = beg + (int)threadIdx.x; i < end; i += 512) {
    uint2 p = pairs[i];
    int slot = rowptr[p.x] + atomicAdd(&fill[p.x], 1);
    csr[slot] = (int)p.y;
  }
}

// ---------------- casts / weight packing ----------------

__global__ void k_cast(const float* __restrict__ in, unsigned short* __restrict__ ob, int n8) {
  int i = blockIdx.x * blockDim.x + threadIdx.x;
  if (i >= n8) return;
  float4 a = *reinterpret_cast<const float4*>(in + (size_t)i * 8);
  float4 b = *reinterpret_cast<const float4*>(in + (size_t)i * 8 + 4);
  uint4 o;
  o.x = (uint32)f2bf(a.x) | ((uint32)f2bf(a.y) << 16);
  o.y = (uint32)f2bf(a.z) | ((uint32)f2bf(a.w) << 16);
  o.z = (uint32)f2bf(b.x) | ((uint32)f2bf(b.y) << 16);
  o.w = (uint32)f2bf(b.z) | ((uint32)f2bf(b.w) << 16);
  *reinterpret_cast<uint4*>(ob + (size_t)i * 8) = o;
}

// Pack W = [Wl ; Wr] (K=256, N=128) into B-fragment order for
// mfma_f32_16x16x32_bf16: B[k = quad*8+j][n = lane&15]. 32768 elements.
__global__ void k_prepw(const float* __restrict__ Wl, const float* __restrict__ Wr,
                        unsigned short* __restrict__ Wp) {
  int t = blockIdx.x * 256 + threadIdx.x;
  if (t >= 256 * 128) return;
  int j = t & 7;
  int lane = (t >> 3) & 63;
  int tile = (t >> 9) & 1;
  int ks = (t >> 10) & 7;
  int ng = (t >> 13) & 3;
  int k = ks * 32 + (lane >> 4) * 8 + j;
  int n = ng * 32 + tile * 16 + (lane & 15);
  float w = (k < 128) ? Wl[k * 128 + n] : Wr[(k - 128) * 128 + n];
  Wp[t] = f2bf(w);
}

// ---------------- mean aggregation, bf16 rows (256B gather) ----------------
__global__ void k_aggb(const unsigned short* __restrict__ hb, const int* __restrict__ rowptr,
                       const int* __restrict__ csr, unsigned short* __restrict__ meanb) {
  int node = blockIdx.x * 16 + (threadIdx.x >> 4);
  int l = threadIdx.x & 15;
  if (node >= N_NODES) return;
  int beg = rowptr[node], end = rowptr[node + 1];
  float acc[8] = {0.f, 0.f, 0.f, 0.f, 0.f, 0.f, 0.f, 0.f};
  for (int e = beg; e < end; ++e) {
    int s = csr[e];
    uint4 v = *reinterpret_cast<const uint4*>(hb + (size_t)s * D + l * 8);
    acc[0] += bflo(v.x); acc[1] += bfhi(v.x);
    acc[2] += bflo(v.y); acc[3] += bfhi(v.y);
    acc[4] += bflo(v.z); acc[5] += bfhi(v.z);
    acc[6] += bflo(v.w); acc[7] += bfhi(v.w);
  }
  float inv = (end > beg) ? 1.0f / (float)(end - beg) : 0.0f;
  uint4 o;
  o.x = (uint32)f2bf(acc[0] * inv) | ((uint32)f2bf(acc[1] * inv) << 16);
  o.y = (uint32)f2bf(acc[2] * inv) | ((uint32)f2bf(acc[3] * inv) << 16);
  o.z = (uint32)f2bf(acc[4] * inv) | ((uint32)f2bf(acc[5] * inv) << 16);
  o.w = (uint32)f2bf(acc[6] * inv) | ((uint32)f2bf(acc[7] * inv) << 16);
  *reinterpret_cast<uint4*>(meanb + (size_t)node * D + l * 8) = o;
}

// ---------------- MFMA GEMM: C[M,128] = [meanb|xh] @ Wp + b ----------------
#define GRID_GEMM 1024

__global__ __launch_bounds__(256) void k_gemm(
    const unsigned short* __restrict__ Am, const unsigned short* __restrict__ Axh,
    const unsigned short* __restrict__ Wp, const float* __restrict__ bias,
    void* __restrict__ outp, int relu_bf16_out, int nTiles) {
  int wave = threadIdx.x >> 6;
  int lane = threadIdx.x & 63;
  int q = lane >> 4;
  int r = lane & 15;

  short8 Bf[8][2];
  const unsigned short* wp = Wp + ((size_t)wave * 8 * 2) * 64 * 8 + lane * 8;
#pragma unroll
  for (int ks = 0; ks < 8; ++ks)
#pragma unroll
    for (int t = 0; t < 2; ++t)
      Bf[ks][t] = *reinterpret_cast<const short8*>(wp + (ks * 2 + t) * 512);

  float bia0 = bias[wave * 32 + r];
  float bia1 = bias[wave * 32 + 16 + r];

  for (int tile = blockIdx.x; tile < nTiles; tile += GRID_GEMM) {
    int row = tile * 16 + r;
    const unsigned short* am = Am + (size_t)row * D + q * 8;
    const unsigned short* ax = Axh + (size_t)row * D + q * 8;
    short8 A[8];
#pragma unroll
    for (int ks = 0; ks < 4; ++ks) A[ks] = *reinterpret_cast<const short8*>(am + ks * 32);
#pragma unroll
    for (int ks = 0; ks < 4; ++ks) A[4 + ks] = *reinterpret_cast<const short8*>(ax + ks * 32);

    f32x4 c0 = {0.f, 0.f, 0.f, 0.f}, c1 = {0.f, 0.f, 0.f, 0.f};
#pragma unroll
    for (int ks = 0; ks < 8; ++ks) {
      c0 = __builtin_amdgcn_mfma_f32_16x16x32_bf16(A[ks], Bf[ks][0], c0, 0, 0, 0);
      c1 = __builtin_amdgcn_mfma_f32_16x16x32_bf16(A[ks], Bf[ks][1], c1, 0, 0, 0);
    }

    int orow = tile * 16 + q * 4;   // C: col=lane&15, row=quad*4+reg
    if (relu_bf16_out) {
      unsigned short* ob = (unsigned short*)outp + (size_t)orow * D + wave * 32 + r;
#pragma unroll
      for (int g = 0; g < 4; ++g) {
        ob[(size_t)g * D] = f2bf(fmaxf(c0[g] + bia0, 0.f));
        ob[(size_t)g * D + 16] = f2bf(fmaxf(c1[g] + bia1, 0.f));
      }
    } else {
      float* of = (float*)outp + (size_t)orow * D + wave * 32 + r;
#pragma unroll
      for (int g = 0; g < 4; ++g) {
        of[(size_t)g * D] = c0[g] + bia0;
        of[(size_t)g * D + 16] = c1[g] + bia1;
      }
    }
  }
}

// ---------------- launch ----------------

extern "C" void kernel_launch(void* const* d_in, const int* in_sizes, int n_in,
                              void* d_out, int out_size, void* d_ws, size_t ws_size,
                              hipStream_t stream) {
  const float* x   = (const float*)d_in[0];
  const int*   ei  = (const int*)d_in[1];
  const float* Wl1 = (const float*)d_in[2];
  const float* Wr1 = (const float*)d_in[3];
  const float* b1  = (const float*)d_in[4];
  const float* Wl2 = (const float*)d_in[5];
  const float* Wr2 = (const float*)d_in[6];
  const float* b2  = (const float*)d_in[7];
  float* out = (float*)d_out;

  const int* esrc = ei;
  const int* edst = ei + N_EDGES;

  char* p = (char*)d_ws;
  auto take = [&](size_t bytes) {
    char* q = p;
    p += (bytes + 255) & ~(size_t)255;
    return q;
  };
  // cnt+fill contiguous: one k_zero(2N) covers both exactly (R2/R3 lesson).
  int* cnt    = (int*)take((size_t)2 * N_NODES * 4);
  int* fill   = cnt + N_NODES;
  int* rowptr = (int*)take((size_t)(N_NODES + 1) * 4);
  int* bsum   = (int*)take(512 * 4);
  int* bfill  = (int*)take(256 * 4);
  int* csr    = (int*)take((size_t)N_EDGES * 4);
  uint2* pairs = (uint2*)take((size_t)N_EDGES * 8);
  unsigned short* xb    = (unsigned short*)take((size_t)N_NODES * D * 2);
  unsigned short* hb    = (unsigned short*)take((size_t)N_NODES * D * 2);
  unsigned short* meanb = (unsigned short*)take((size_t)N_NODES * D * 2);
  unsigned short* Wp1   = (unsigned short*)take(256 * 128 * 2);
  unsigned short* Wp2   = (unsigned short*)take(256 * 128 * 2);

  const int nscan = (N_NODES + 255) / 256;          // 391
  const int nTiles = N_NODES / 16;                  // 6250
  const int npart = (N_EDGES + PCHUNK - 1) / PCHUNK; // 391

  // CSR build (shared by both layers)
  k_zero<<<(2 * N_NODES + 255) / 256, 256, 0, stream>>>(cnt, 2 * N_NODES);
  k_count<<<(N_EDGES + 255) / 256, 256, 0, stream>>>(edst, cnt);
  k_scan1<<<nscan, 256, 0, stream>>>(cnt, rowptr, bsum, N_NODES);
  k_scan2<<<1, 512, 0, stream>>>(bsum, nscan);
  k_scan3<<<nscan, 256, 0, stream>>>(rowptr, bsum, N_NODES);
  k_binit<<<1, 256, 0, stream>>>(rowptr, bfill);
  k_part<<<npart, 256, 0, stream>>>(esrc, edst, bfill, pairs);
  k_fill2<<<NBUCK, 512, 0, stream>>>(pairs, rowptr, fill, csr);

  // bf16 prep
  k_cast<<<(N_NODES * D / 8 + 255) / 256, 256, 0, stream>>>(x, xb, N_NODES * D / 8);
  k_prepw<<<128, 256, 0, stream>>>(Wl1, Wr1, Wp1);
  k_prepw<<<128, 256, 0, stream>>>(Wl2, Wr2, Wp2);

  // layer 1: hb = relu([mean(xb)|xb] @ Wp1 + b1)   (bf16 out)
  k_aggb<<<(N_NODES + 15) / 16, 256, 0, stream>>>(xb, rowptr, csr, meanb);
  k_gemm<<<GRID_GEMM, 256, 0, stream>>>(meanb, xb, Wp1, b1, hb, 1, nTiles);

  // layer 2: out = [mean(hb)|hb] @ Wp2 + b2        (f32 out)
  k_aggb<<<(N_NODES + 15) / 16, 256, 0, stream>>>(hb, rowptr, csr, meanb);
  k_gemm<<<GRID_GEMM, 256, 0, stream>>>(meanb, hb, Wp2, b2, out, 0, nTiles);
}

// Round 6
// 331.695 us; speedup vs baseline: 2.2592x; 1.3495x over previous
//
#include <hip/hip_runtime.h>
#include <stdint.h>

#define N_NODES 100000
#define N_EDGES 1600000
#define D 128
#define NBUCK 196          // ceil(N_NODES/512); bucket b = dst >> 9
#define BSTRIDE 9216       // fixed pairs region per bucket (mean 8163, +11 sigma)
#define PCHUNK 4096        // edges per k_part block
#define NTILES (N_NODES / 16)   // 6250 exact
#define GRID_AG 2048

typedef unsigned int uint32;
typedef __attribute__((ext_vector_type(8))) short short8;   // 8 bf16 = 4 VGPRs
typedef __attribute__((ext_vector_type(4))) float f32x4;

__device__ __forceinline__ unsigned short f2bf(float f) {
  unsigned u = __builtin_bit_cast(unsigned, f);
  u += 0x7fffu + ((u >> 16) & 1u);          // round-to-nearest-even
  return (unsigned short)(u >> 16);
}
__device__ __forceinline__ float bflo(unsigned v) {
  return __builtin_bit_cast(float, v << 16);
}
__device__ __forceinline__ float bfhi(unsigned v) {
  return __builtin_bit_cast(float, v & 0xffff0000u);
}

// ---------------- CSR build (2 passes over edges, no global histogram) ------

__global__ void k_zero(int* __restrict__ p, int n) {
  int i = blockIdx.x * blockDim.x + threadIdx.x;
  if (i < n) p[i] = 0;
}

// Partition edges into NBUCK dst-buckets as (dst,src) pairs, coalesced runs.
__global__ __launch_bounds__(256) void k_part(const int* __restrict__ src,
                                              const int* __restrict__ dst,
                                              int* __restrict__ bcnt,
                                              uint2* __restrict__ pairs) {
  __shared__ uint2 buff[PCHUNK];     // 32 KB
  __shared__ uint2 sorted[PCHUNK];   // 32 KB
  __shared__ int hist[256], stmp[256], loff[256], cpos[256], base[256];
  int tid = threadIdx.x;
  int e0 = blockIdx.x * PCHUNK;
  int nv = N_EDGES - e0;
  if (nv > PCHUNK) nv = PCHUNK;

  hist[tid] = 0;
  __syncthreads();
  for (int i = tid; i < nv; i += 256) {
    int d = dst[e0 + i];
    int s = src[e0 + i];
    buff[i] = make_uint2((uint32)d, (uint32)s);
    atomicAdd(&hist[d >> 9], 1);
  }
  __syncthreads();
  int v = hist[tid];
  stmp[tid] = v;
  __syncthreads();
  for (int off = 1; off < 256; off <<= 1) {
    int t = (tid >= off) ? stmp[tid - off] : 0;
    __syncthreads();
    stmp[tid] += t;
    __syncthreads();
  }
  loff[tid] = stmp[tid] - v;
  cpos[tid] = stmp[tid] - v;
  base[tid] = (v > 0) ? atomicAdd(&bcnt[tid], v) : 0;   // reserve run in bucket region
  __syncthreads();
  for (int i = tid; i < nv; i += 256) {
    uint2 p = buff[i];
    int r = atomicAdd(&cpos[p.x >> 9], 1);
    sorted[r] = p;
  }
  __syncthreads();
  for (int i = tid; i < nv; i += 256) {
    uint2 p = sorted[i];
    int b = (int)(p.x >> 9);
    int local = base[b] + (i - loff[b]);
    if (local < BSTRIDE)                                // det. input: never trips
      pairs[(size_t)b * BSTRIDE + local] = p;
  }
}

// exclusive scan of 196 bucket counts -> bbase[0..196]
__global__ void k_scanb(const int* __restrict__ bcnt, int* __restrict__ bbase) {
  __shared__ int s[256];
  int tid = threadIdx.x;
  int v = (tid < NBUCK) ? bcnt[tid] : 0;
  s[tid] = v;
  __syncthreads();
  for (int off = 1; off < 256; off <<= 1) {
    int t = (tid >= off) ? s[tid - off] : 0;
    __syncthreads();
    s[tid] += t;
    __syncthreads();
  }
  if (tid <= NBUCK) bbase[tid] = s[tid] - v;   // v=0 at tid==NBUCK -> total
}

// Per-bucket: LDS hist(512) -> scan -> write rowptr slice + scatter csr.
__global__ __launch_bounds__(512) void k_csr(const uint2* __restrict__ pairs,
                                             const int* __restrict__ bcnt,
                                             const int* __restrict__ bbase,
                                             int* __restrict__ rowptr,
                                             int* __restrict__ csr) {
  __shared__ int hist[512], off[512], cur[512];
  int b = blockIdx.x;
  int tid = threadIdx.x;
  int lo = b << 9;
  int hi = lo + 512;
  if (hi > N_NODES) hi = N_NODES;
  int ne = bcnt[b];
  if (ne > BSTRIDE) ne = BSTRIDE;
  const uint2* pb = pairs + (size_t)b * BSTRIDE;
  int bb = bbase[b];

  hist[tid] = 0;
  __syncthreads();
  for (int i = tid; i < ne; i += 512) atomicAdd(&hist[(int)pb[i].x - lo], 1);
  __syncthreads();
  int v = hist[tid];
  off[tid] = v;
  __syncthreads();
  for (int o = 1; o < 512; o <<= 1) {
    int t = (tid >= o) ? off[tid - o] : 0;
    __syncthreads();
    off[tid] += t;
    __syncthreads();
  }
  off[tid] -= v;               // exclusive
  cur[tid] = off[tid];
  if (lo + tid < hi) rowptr[lo + tid] = bb + off[tid];
  if (b == NBUCK - 1 && tid == 0) rowptr[N_NODES] = bbase[NBUCK];
  __syncthreads();
  for (int i = tid; i < ne; i += 512) {
    int d = (int)pb[i].x - lo;
    int slot = atomicAdd(&cur[d], 1);
    csr[bb + slot] = (int)pb[i].y;
  }
}

// ---------------- casts / weight packing ----------------

__global__ void k_cast(const float* __restrict__ in, unsigned short* __restrict__ ob, int n8) {
  int i = blockIdx.x * blockDim.x + threadIdx.x;
  if (i >= n8) return;
  float4 a = *reinterpret_cast<const float4*>(in + (size_t)i * 8);
  float4 b = *reinterpret_cast<const float4*>(in + (size_t)i * 8 + 4);
  uint4 o;
  o.x = (uint32)f2bf(a.x) | ((uint32)f2bf(a.y) << 16);
  o.y = (uint32)f2bf(a.z) | ((uint32)f2bf(a.w) << 16);
  o.z = (uint32)f2bf(b.x) | ((uint32)f2bf(b.y) << 16);
  o.w = (uint32)f2bf(b.z) | ((uint32)f2bf(b.w) << 16);
  *reinterpret_cast<uint4*>(ob + (size_t)i * 8) = o;
}

// Pack W = [Wl ; Wr] (K=256, N=128) into B-fragment order for
// mfma_f32_16x16x32_bf16: B[k = quad*8+j][n = lane&15]. 32768 elements.
__global__ void k_prepw(const float* __restrict__ Wl, const float* __restrict__ Wr,
                        unsigned short* __restrict__ Wp) {
  int t = blockIdx.x * 256 + threadIdx.x;
  if (t >= 256 * 128) return;
  int j = t & 7;
  int lane = (t >> 3) & 63;
  int tile = (t >> 9) & 1;
  int ks = (t >> 10) & 7;
  int ng = (t >> 13) & 3;
  int k = ks * 32 + (lane >> 4) * 8 + j;
  int n = ng * 32 + tile * 16 + (lane & 15);
  float w = (k < 128) ? Wl[k * 128 + n] : Wr[(k - 128) * 128 + n];
  Wp[t] = f2bf(w);
}

// ---------------- fused mean-aggregate + MFMA GEMM ----------------
// Per 16-node tile: 16-thread groups gather+mean into LDS (f32), then the
// 4 waves compute [mean|x] @ Wp with register-resident B fragments.
__global__ __launch_bounds__(256) void k_agg_gemm(
    const unsigned short* __restrict__ table,   // gather table AND x-half rows
    const int* __restrict__ rowptr, const int* __restrict__ csr,
    const unsigned short* __restrict__ Wp, const float* __restrict__ bias,
    void* __restrict__ outp, int relu_bf16_out) {
  __shared__ float meanS[16][132];   // +4 pad: A-frag column reads 2-way free
  int tid = threadIdx.x;
  int wave = tid >> 6;
  int lane = tid & 63;
  int q = lane >> 4;
  int r = lane & 15;
  int g = tid >> 4;      // node group 0..15 (phase 1)
  int l = tid & 15;      // 16B lane within node (phase 1)

  short8 Bf[8][2];
  const unsigned short* wp = Wp + ((size_t)wave * 8 * 2) * 64 * 8 + lane * 8;
#pragma unroll
  for (int ks = 0; ks < 8; ++ks)
#pragma unroll
    for (int t = 0; t < 2; ++t)
      Bf[ks][t] = *reinterpret_cast<const short8*>(wp + (ks * 2 + t) * 512);

  float bia0 = bias[wave * 32 + r];
  float bia1 = bias[wave * 32 + 16 + r];

  for (int tile = blockIdx.x; tile < NTILES; tile += GRID_AG) {
    // ---- phase 1: mean of in-neighbors for 16 nodes -> LDS (f32) ----
    int node = tile * 16 + g;
    int beg = rowptr[node], end = rowptr[node + 1];
    float acc[8] = {0.f, 0.f, 0.f, 0.f, 0.f, 0.f, 0.f, 0.f};
    int e = beg;
    for (; e + 1 < end; e += 2) {   // 2-way unroll: keep >=2 gathers in flight
      int s0 = csr[e], s1 = csr[e + 1];
      uint4 v0 = *reinterpret_cast<const uint4*>(table + (size_t)s0 * D + l * 8);
      uint4 v1 = *reinterpret_cast<const uint4*>(table + (size_t)s1 * D + l * 8);
      acc[0] += bflo(v0.x); acc[1] += bfhi(v0.x);
      acc[2] += bflo(v0.y); acc[3] += bfhi(v0.y);
      acc[4] += bflo(v0.z); acc[5] += bfhi(v0.z);
      acc[6] += bflo(v0.w); acc[7] += bfhi(v0.w);
      acc[0] += bflo(v1.x); acc[1] += bfhi(v1.x);
      acc[2] += bflo(v1.y); acc[3] += bfhi(v1.y);
      acc[4] += bflo(v1.z); acc[5] += bfhi(v1.z);
      acc[6] += bflo(v1.w); acc[7] += bfhi(v1.w);
    }
    if (e < end) {
      int s0 = csr[e];
      uint4 v0 = *reinterpret_cast<const uint4*>(table + (size_t)s0 * D + l * 8);
      acc[0] += bflo(v0.x); acc[1] += bfhi(v0.x);
      acc[2] += bflo(v0.y); acc[3] += bfhi(v0.y);
      acc[4] += bflo(v0.z); acc[5] += bfhi(v0.z);
      acc[6] += bflo(v0.w); acc[7] += bfhi(v0.w);
    }
    float inv = (end > beg) ? 1.0f / (float)(end - beg) : 0.0f;
    float4 m0 = make_float4(acc[0] * inv, acc[1] * inv, acc[2] * inv, acc[3] * inv);
    float4 m1 = make_float4(acc[4] * inv, acc[5] * inv, acc[6] * inv, acc[7] * inv);
    *reinterpret_cast<float4*>(&meanS[g][l * 8]) = m0;
    *reinterpret_cast<float4*>(&meanS[g][l * 8 + 4]) = m1;
    __syncthreads();

    // ---- phase 2: [mean | x] @ Wp ----
    short8 A[8];
#pragma unroll
    for (int ks = 0; ks < 4; ++ks) {     // mean half (k = 0..127) from LDS
      float4 a0 = *reinterpret_cast<const float4*>(&meanS[r][ks * 32 + q * 8]);
      float4 a1 = *reinterpret_cast<const float4*>(&meanS[r][ks * 32 + q * 8 + 4]);
      short8 a;
      a[0] = (short)f2bf(a0.x); a[1] = (short)f2bf(a0.y);
      a[2] = (short)f2bf(a0.z); a[3] = (short)f2bf(a0.w);
      a[4] = (short)f2bf(a1.x); a[5] = (short)f2bf(a1.y);
      a[6] = (short)f2bf(a1.z); a[7] = (short)f2bf(a1.w);
      A[ks] = a;
    }
    const unsigned short* ax = table + (size_t)(tile * 16 + r) * D + q * 8;
#pragma unroll
    for (int ks = 0; ks < 4; ++ks)       // x half (k = 128..255) from global
      A[4 + ks] = *reinterpret_cast<const short8*>(ax + ks * 32);

    f32x4 c0 = {0.f, 0.f, 0.f, 0.f}, c1 = {0.f, 0.f, 0.f, 0.f};
#pragma unroll
    for (int ks = 0; ks < 8; ++ks) {
      c0 = __builtin_amdgcn_mfma_f32_16x16x32_bf16(A[ks], Bf[ks][0], c0, 0, 0, 0);
      c1 = __builtin_amdgcn_mfma_f32_16x16x32_bf16(A[ks], Bf[ks][1], c1, 0, 0, 0);
    }

    int orow = tile * 16 + q * 4;   // C: col=lane&15, row=quad*4+reg
    if (relu_bf16_out) {
      unsigned short* ob = (unsigned short*)outp + (size_t)orow * D + wave * 32 + r;
#pragma unroll
      for (int gg = 0; gg < 4; ++gg) {
        ob[(size_t)gg * D] = f2bf(fmaxf(c0[gg] + bia0, 0.f));
        ob[(size_t)gg * D + 16] = f2bf(fmaxf(c1[gg] + bia1, 0.f));
      }
    } else {
      float* of = (float*)outp + (size_t)orow * D + wave * 32 + r;
#pragma unroll
      for (int gg = 0; gg < 4; ++gg) {
        of[(size_t)gg * D] = c0[gg] + bia0;
        of[(size_t)gg * D + 16] = c1[gg] + bia1;
      }
    }
    __syncthreads();   // meanS reused next tile
  }
}

// ---------------- launch ----------------

extern "C" void kernel_launch(void* const* d_in, const int* in_sizes, int n_in,
                              void* d_out, int out_size, void* d_ws, size_t ws_size,
                              hipStream_t stream) {
  const float* x   = (const float*)d_in[0];
  const int*   ei  = (const int*)d_in[1];
  const float* Wl1 = (const float*)d_in[2];
  const float* Wr1 = (const float*)d_in[3];
  const float* b1  = (const float*)d_in[4];
  const float* Wl2 = (const float*)d_in[5];
  const float* Wr2 = (const float*)d_in[6];
  const float* b2  = (const float*)d_in[7];
  float* out = (float*)d_out;

  const int* esrc = ei;
  const int* edst = ei + N_EDGES;

  char* p = (char*)d_ws;
  auto take = [&](size_t bytes) {
    char* q = p;
    p += (bytes + 255) & ~(size_t)255;
    return q;
  };
  int* bcnt   = (int*)take(256 * 4);
  int* bbase  = (int*)take(257 * 4);
  int* rowptr = (int*)take((size_t)(N_NODES + 1) * 4);
  int* csr    = (int*)take((size_t)N_EDGES * 4);
  uint2* pairs = (uint2*)take((size_t)NBUCK * BSTRIDE * 8);   // 14.5 MB
  unsigned short* xb  = (unsigned short*)take((size_t)N_NODES * D * 2);
  unsigned short* hb  = (unsigned short*)take((size_t)N_NODES * D * 2);
  unsigned short* Wp1 = (unsigned short*)take(256 * 128 * 2);
  unsigned short* Wp2 = (unsigned short*)take(256 * 128 * 2);

  const int npart = (N_EDGES + PCHUNK - 1) / PCHUNK;   // 391

  // CSR build: partition -> bucket-base scan -> per-bucket rowptr+csr
  k_zero<<<1, 256, 0, stream>>>(bcnt, 256);
  k_part<<<npart, 256, 0, stream>>>(esrc, edst, bcnt, pairs);
  k_scanb<<<1, 256, 0, stream>>>(bcnt, bbase);
  k_csr<<<NBUCK, 512, 0, stream>>>(pairs, bcnt, bbase, rowptr, csr);

  // bf16 prep
  k_cast<<<(N_NODES * D / 8 + 255) / 256, 256, 0, stream>>>(x, xb, N_NODES * D / 8);
  k_prepw<<<128, 256, 0, stream>>>(Wl1, Wr1, Wp1);
  k_prepw<<<128, 256, 0, stream>>>(Wl2, Wr2, Wp2);

  // layer 1: hb = relu([mean(xb)|xb] @ Wp1 + b1)   (bf16 out)
  k_agg_gemm<<<GRID_AG, 256, 0, stream>>>(xb, rowptr, csr, Wp1, b1, hb, 1);
  // layer 2: out = [mean(hb)|hb] @ Wp2 + b2        (f32 out)
  k_agg_gemm<<<GRID_AG, 256, 0, stream>>>(hb, rowptr, csr, Wp2, b2, out, 0);
}

// Round 7
// 330.283 us; speedup vs baseline: 2.2688x; 1.0043x over previous
//
#include <hip/hip_runtime.h>
#include <stdint.h>

#define N_NODES 100000
#define N_EDGES 1600000
#define D 128
#define NBUCK 196          // ceil(N_NODES/512); bucket b = dst >> 9
#define BSTRIDE 9216       // fixed pairs region per bucket (mean 8163, +11 sigma)
#define PCHUNK 2048        // edges per k_part block (16KB x2 LDS -> 4 blocks/CU)
#define NTILES (N_NODES / 16)   // 6250 exact
#define GRID_AG 2048

typedef unsigned int uint32;
typedef __attribute__((ext_vector_type(8))) short short8;   // 8 bf16 = 4 VGPRs
typedef __attribute__((ext_vector_type(4))) float f32x4;

__device__ __forceinline__ unsigned short f2bf(float f) {
  unsigned u = __builtin_bit_cast(unsigned, f);
  u += 0x7fffu + ((u >> 16) & 1u);          // round-to-nearest-even
  return (unsigned short)(u >> 16);
}
__device__ __forceinline__ float bflo(unsigned v) {
  return __builtin_bit_cast(float, v << 16);
}
__device__ __forceinline__ float bfhi(unsigned v) {
  return __builtin_bit_cast(float, v & 0xffff0000u);
}

// ---------------- CSR build (2 passes over edges, no global histogram) ------

// Partition edges into NBUCK dst-buckets as (dst,src) pairs, coalesced runs.
__global__ __launch_bounds__(256) void k_part(const int* __restrict__ src,
                                              const int* __restrict__ dst,
                                              int* __restrict__ bcnt,
                                              uint2* __restrict__ pairs) {
  __shared__ uint2 buff[PCHUNK];     // 16 KB
  __shared__ uint2 sorted[PCHUNK];   // 16 KB
  __shared__ int hist[256], stmp[256], loff[256], cpos[256], base[256];
  int tid = threadIdx.x;
  int e0 = blockIdx.x * PCHUNK;
  int nv = N_EDGES - e0;
  if (nv > PCHUNK) nv = PCHUNK;

  hist[tid] = 0;
  __syncthreads();
  for (int i = tid; i < nv; i += 256) {
    int d = dst[e0 + i];
    int s = src[e0 + i];
    buff[i] = make_uint2((uint32)d, (uint32)s);
    atomicAdd(&hist[d >> 9], 1);
  }
  __syncthreads();
  int v = hist[tid];
  stmp[tid] = v;
  __syncthreads();
  for (int off = 1; off < 256; off <<= 1) {
    int t = (tid >= off) ? stmp[tid - off] : 0;
    __syncthreads();
    stmp[tid] += t;
    __syncthreads();
  }
  loff[tid] = stmp[tid] - v;
  cpos[tid] = stmp[tid] - v;
  base[tid] = (v > 0) ? atomicAdd(&bcnt[tid], v) : 0;   // reserve run in bucket region
  __syncthreads();
  for (int i = tid; i < nv; i += 256) {
    uint2 p = buff[i];
    int r = atomicAdd(&cpos[p.x >> 9], 1);
    sorted[r] = p;
  }
  __syncthreads();
  for (int i = tid; i < nv; i += 256) {
    uint2 p = sorted[i];
    int b = (int)(p.x >> 9);
    int local = base[b] + (i - loff[b]);
    if (local < BSTRIDE)                                // det. input: never trips
      pairs[(size_t)b * BSTRIDE + local] = p;
  }
}

// exclusive scan of 196 bucket counts -> bbase[0..196]
__global__ void k_scanb(const int* __restrict__ bcnt, int* __restrict__ bbase) {
  __shared__ int s[256];
  int tid = threadIdx.x;
  int v = (tid < NBUCK) ? bcnt[tid] : 0;
  s[tid] = v;
  __syncthreads();
  for (int off = 1; off < 256; off <<= 1) {
    int t = (tid >= off) ? s[tid - off] : 0;
    __syncthreads();
    s[tid] += t;
    __syncthreads();
  }
  if (tid <= NBUCK) bbase[tid] = s[tid] - v;   // v=0 at tid==NBUCK -> total
}

// Per-bucket: LDS hist(512) -> scan -> write rowptr slice + scatter csr.
__global__ __launch_bounds__(512) void k_csr(const uint2* __restrict__ pairs,
                                             const int* __restrict__ bcnt,
                                             const int* __restrict__ bbase,
                                             int* __restrict__ rowptr,
                                             int* __restrict__ csr) {
  __shared__ int hist[512], off[512], cur[512];
  int b = blockIdx.x;
  int tid = threadIdx.x;
  int lo = b << 9;
  int hi = lo + 512;
  if (hi > N_NODES) hi = N_NODES;
  int ne = bcnt[b];
  if (ne > BSTRIDE) ne = BSTRIDE;
  const uint2* pb = pairs + (size_t)b * BSTRIDE;
  int bb = bbase[b];

  hist[tid] = 0;
  __syncthreads();
  for (int i = tid; i < ne; i += 512) atomicAdd(&hist[(int)pb[i].x - lo], 1);
  __syncthreads();
  int v = hist[tid];
  off[tid] = v;
  __syncthreads();
  for (int o = 1; o < 512; o <<= 1) {
    int t = (tid >= o) ? off[tid - o] : 0;
    __syncthreads();
    off[tid] += t;
    __syncthreads();
  }
  off[tid] -= v;               // exclusive
  cur[tid] = off[tid];
  if (lo + tid < hi) rowptr[lo + tid] = bb + off[tid];
  if (b == NBUCK - 1 && tid == 0) rowptr[N_NODES] = bbase[NBUCK];
  __syncthreads();
  for (int i = tid; i < ne; i += 512) {
    int d = (int)pb[i].x - lo;
    int slot = atomicAdd(&cur[d], 1);
    csr[bb + slot] = (int)pb[i].y;
  }
}

// ---------------- casts / weight packing ----------------

__global__ void k_cast(const float* __restrict__ in, unsigned short* __restrict__ ob, int n8) {
  int i = blockIdx.x * blockDim.x + threadIdx.x;
  if (i >= n8) return;
  float4 a = *reinterpret_cast<const float4*>(in + (size_t)i * 8);
  float4 b = *reinterpret_cast<const float4*>(in + (size_t)i * 8 + 4);
  uint4 o;
  o.x = (uint32)f2bf(a.x) | ((uint32)f2bf(a.y) << 16);
  o.y = (uint32)f2bf(a.z) | ((uint32)f2bf(a.w) << 16);
  o.z = (uint32)f2bf(b.x) | ((uint32)f2bf(b.y) << 16);
  o.w = (uint32)f2bf(b.z) | ((uint32)f2bf(b.w) << 16);
  *reinterpret_cast<uint4*>(ob + (size_t)i * 8) = o;
}

// Pack BOTH layers' W = [Wl ; Wr] (K=256, N=128) into B-fragment order for
// mfma_f32_16x16x32_bf16: B[k = quad*8+j][n = lane&15]. 32768 elements each.
__global__ void k_prepw2(const float* __restrict__ Wl1, const float* __restrict__ Wr1,
                         const float* __restrict__ Wl2, const float* __restrict__ Wr2,
                         unsigned short* __restrict__ Wp1,
                         unsigned short* __restrict__ Wp2) {
  int t = blockIdx.x * 256 + threadIdx.x;   // 65536
  int which = t >> 15;
  int tt = t & 32767;
  int j = tt & 7;
  int lane = (tt >> 3) & 63;
  int tile = (tt >> 9) & 1;
  int ks = (tt >> 10) & 7;
  int ng = (tt >> 13) & 3;
  int k = ks * 32 + (lane >> 4) * 8 + j;
  int n = ng * 32 + tile * 16 + (lane & 15);
  const float* Wl = which ? Wl2 : Wl1;
  const float* Wr = which ? Wr2 : Wr1;
  float w = (k < 128) ? Wl[k * 128 + n] : Wr[(k - 128) * 128 + n];
  (which ? Wp2 : Wp1)[tt] = f2bf(w);
}

// ---------------- fused mean-aggregate + MFMA GEMM ----------------
// Per 16-node tile: 16-thread groups gather+mean into LDS (f32), then the
// 4 waves compute [mean|x] @ Wp with register-resident B fragments.
#define ACC8(v)                                          \
  acc[0] += bflo(v.x); acc[1] += bfhi(v.x);              \
  acc[2] += bflo(v.y); acc[3] += bfhi(v.y);              \
  acc[4] += bflo(v.z); acc[5] += bfhi(v.z);              \
  acc[6] += bflo(v.w); acc[7] += bfhi(v.w);

__global__ __launch_bounds__(256) void k_agg_gemm(
    const unsigned short* __restrict__ table,   // gather table AND x-half rows
    const int* __restrict__ rowptr, const int* __restrict__ csr,
    const unsigned short* __restrict__ Wp, const float* __restrict__ bias,
    void* __restrict__ outp, int relu_bf16_out) {
  __shared__ float meanS[16][132];   // +4 pad
  int tid = threadIdx.x;
  int wave = tid >> 6;
  int lane = tid & 63;
  int q = lane >> 4;
  int r = lane & 15;
  int g = tid >> 4;      // node group 0..15 (phase 1)
  int l = tid & 15;      // 16B lane within node (phase 1)

  short8 Bf[8][2];
  const unsigned short* wp = Wp + ((size_t)wave * 8 * 2) * 64 * 8 + lane * 8;
#pragma unroll
  for (int ks = 0; ks < 8; ++ks)
#pragma unroll
    for (int t = 0; t < 2; ++t)
      Bf[ks][t] = *reinterpret_cast<const short8*>(wp + (ks * 2 + t) * 512);

  float bia0 = bias[wave * 32 + r];
  float bia1 = bias[wave * 32 + 16 + r];

  for (int tile = blockIdx.x; tile < NTILES; tile += GRID_AG) {
    // x-half A-frags: independent of the gather -> issue first, overlap latency
    const unsigned short* ax = table + (size_t)(tile * 16 + r) * D + q * 8;
    short8 A[8];
#pragma unroll
    for (int ks = 0; ks < 4; ++ks)
      A[4 + ks] = *reinterpret_cast<const short8*>(ax + ks * 32);

    // ---- phase 1: mean of in-neighbors for 16 nodes -> LDS (f32) ----
    int node = tile * 16 + g;
    int beg = rowptr[node], end = rowptr[node + 1];
    float acc[8] = {0.f, 0.f, 0.f, 0.f, 0.f, 0.f, 0.f, 0.f};
    int e = beg;
    for (; e + 3 < end; e += 4) {    // 4 gathers in flight
      int s0 = csr[e], s1 = csr[e + 1], s2 = csr[e + 2], s3 = csr[e + 3];
      uint4 v0 = *reinterpret_cast<const uint4*>(table + (size_t)s0 * D + l * 8);
      uint4 v1 = *reinterpret_cast<const uint4*>(table + (size_t)s1 * D + l * 8);
      uint4 v2 = *reinterpret_cast<const uint4*>(table + (size_t)s2 * D + l * 8);
      uint4 v3 = *reinterpret_cast<const uint4*>(table + (size_t)s3 * D + l * 8);
      ACC8(v0) ACC8(v1) ACC8(v2) ACC8(v3)
    }
    for (; e < end; ++e) {
      int s0 = csr[e];
      uint4 v0 = *reinterpret_cast<const uint4*>(table + (size_t)s0 * D + l * 8);
      ACC8(v0)
    }
    float inv = (end > beg) ? 1.0f / (float)(end - beg) : 0.0f;
    float4 m0 = make_float4(acc[0] * inv, acc[1] * inv, acc[2] * inv, acc[3] * inv);
    float4 m1 = make_float4(acc[4] * inv, acc[5] * inv, acc[6] * inv, acc[7] * inv);
    *reinterpret_cast<float4*>(&meanS[g][l * 8]) = m0;
    *reinterpret_cast<float4*>(&meanS[g][l * 8 + 4]) = m1;
    __syncthreads();

    // ---- phase 2: [mean | x] @ Wp ----
#pragma unroll
    for (int ks = 0; ks < 4; ++ks) {     // mean half (k = 0..127) from LDS
      float4 a0 = *reinterpret_cast<const float4*>(&meanS[r][ks * 32 + q * 8]);
      float4 a1 = *reinterpret_cast<const float4*>(&meanS[r][ks * 32 + q * 8 + 4]);
      short8 a;
      a[0] = (short)f2bf(a0.x); a[1] = (short)f2bf(a0.y);
      a[2] = (short)f2bf(a0.z); a[3] = (short)f2bf(a0.w);
      a[4] = (short)f2bf(a1.x); a[5] = (short)f2bf(a1.y);
      a[6] = (short)f2bf(a1.z); a[7] = (short)f2bf(a1.w);
      A[ks] = a;
    }

    f32x4 c0 = {0.f, 0.f, 0.f, 0.f}, c1 = {0.f, 0.f, 0.f, 0.f};
#pragma unroll
    for (int ks = 0; ks < 8; ++ks) {
      c0 = __builtin_amdgcn_mfma_f32_16x16x32_bf16(A[ks], Bf[ks][0], c0, 0, 0, 0);
      c1 = __builtin_amdgcn_mfma_f32_16x16x32_bf16(A[ks], Bf[ks][1], c1, 0, 0, 0);
    }

    int orow = tile * 16 + q * 4;   // C: col=lane&15, row=quad*4+reg
    if (relu_bf16_out) {
      unsigned short* ob = (unsigned short*)outp + (size_t)orow * D + wave * 32 + r;
#pragma unroll
      for (int gg = 0; gg < 4; ++gg) {
        ob[(size_t)gg * D] = f2bf(fmaxf(c0[gg] + bia0, 0.f));
        ob[(size_t)gg * D + 16] = f2bf(fmaxf(c1[gg] + bia1, 0.f));
      }
    } else {
      float* of = (float*)outp + (size_t)orow * D + wave * 32 + r;
#pragma unroll
      for (int gg = 0; gg < 4; ++gg) {
        of[(size_t)gg * D] = c0[gg] + bia0;
        of[(size_t)gg * D + 16] = c1[gg] + bia1;
      }
    }
    __syncthreads();   // meanS reused next tile
  }
}

// ---------------- launch ----------------

extern "C" void kernel_launch(void* const* d_in, const int* in_sizes, int n_in,
                              void* d_out, int out_size, void* d_ws, size_t ws_size,
                              hipStream_t stream) {
  const float* x   = (const float*)d_in[0];
  const int*   ei  = (const int*)d_in[1];
  const float* Wl1 = (const float*)d_in[2];
  const float* Wr1 = (const float*)d_in[3];
  const float* b1  = (const float*)d_in[4];
  const float* Wl2 = (const float*)d_in[5];
  const float* Wr2 = (const float*)d_in[6];
  const float* b2  = (const float*)d_in[7];
  float* out = (float*)d_out;

  const int* esrc = ei;
  const int* edst = ei + N_EDGES;

  char* p = (char*)d_ws;
  auto take = [&](size_t bytes) {
    char* q = p;
    p += (bytes + 255) & ~(size_t)255;
    return q;
  };
  int* bcnt   = (int*)take(256 * 4);
  int* bbase  = (int*)take(257 * 4);
  int* rowptr = (int*)take((size_t)(N_NODES + 1) * 4);
  int* csr    = (int*)take((size_t)N_EDGES * 4);
  uint2* pairs = (uint2*)take((size_t)NBUCK * BSTRIDE * 8);   // 14.5 MB
  unsigned short* xb  = (unsigned short*)take((size_t)N_NODES * D * 2);
  unsigned short* hb  = (unsigned short*)take((size_t)N_NODES * D * 2);
  unsigned short* Wp1 = (unsigned short*)take(256 * 128 * 2);
  unsigned short* Wp2 = (unsigned short*)take(256 * 128 * 2);

  const int npart = (N_EDGES + PCHUNK - 1) / PCHUNK;   // 782

  // CSR build: partition -> bucket-base scan -> per-bucket rowptr+csr
  hipMemsetAsync(bcnt, 0, 256 * 4, stream);
  k_part<<<npart, 256, 0, stream>>>(esrc, edst, bcnt, pairs);
  k_scanb<<<1, 256, 0, stream>>>(bcnt, bbase);
  k_csr<<<NBUCK, 512, 0, stream>>>(pairs, bcnt, bbase, rowptr, csr);

  // bf16 prep
  k_cast<<<(N_NODES * D / 8 + 255) / 256, 256, 0, stream>>>(x, xb, N_NODES * D / 8);
  k_prepw2<<<256, 256, 0, stream>>>(Wl1, Wr1, Wl2, Wr2, Wp1, Wp2);

  // layer 1: hb = relu([mean(xb)|xb] @ Wp1 + b1)   (bf16 out)
  k_agg_gemm<<<GRID_AG, 256, 0, stream>>>(xb, rowptr, csr, Wp1, b1, hb, 1);
  // layer 2: out = [mean(hb)|hb] @ Wp2 + b2        (f32 out)
  k_agg_gemm<<<GRID_AG, 256, 0, stream>>>(hb, rowptr, csr, Wp2, b2, out, 0);
}